// Round 1
// baseline (7200.660 us; speedup 1.0000x reference)
//
#include <hip/hip_runtime.h>
#include <hip/hip_bf16.h>
#include <math.h>

// Problem constants (fixed by reference)
#define B 128
#define R 36
#define VIS 2048
#define MM 1024
#define E 512
#define ATT 512
#define D 1024
#define V 10000
#define MAXLEN 20
#define T 19          // MAXLEN - 1
#define G4 4096       // 4*D
#define XDIM 2560     // VIS + E

#define TILE 64
#define KT 16

__device__ __forceinline__ float sigmoidf_(float x) { return 1.0f / (1.0f + expf(-x)); }

// Generic C[M,N] = A[M,K] @ W[N,K]^T (+bias) (+= C if accumulate)
__global__ __launch_bounds__(256) void gemm_nt(
    const float* __restrict__ A, const float* __restrict__ W,
    const float* __restrict__ bias, float* __restrict__ C,
    int M, int N, int K, int accumulate)
{
    __shared__ float As[KT][TILE];
    __shared__ float Ws[KT][TILE];
    const int tid = threadIdx.x;
    const int tx = tid & 15, ty = tid >> 4;
    const int m0 = blockIdx.y * TILE;
    const int n0 = blockIdx.x * TILE;
    const int lr = tid >> 2;         // 0..63 (row within tile)
    const int lc = (tid & 3) * 4;    // 0,4,8,12 (k within tile)
    float acc[4][4] = {};

    for (int kk = 0; kk < K; kk += KT) {
        {
            int m = m0 + lr;
            float4 v = make_float4(0.f, 0.f, 0.f, 0.f);
            if (m < M) v = *(const float4*)(A + (size_t)m * K + kk + lc);
            As[lc + 0][lr] = v.x; As[lc + 1][lr] = v.y;
            As[lc + 2][lr] = v.z; As[lc + 3][lr] = v.w;
        }
        {
            int n = n0 + lr;
            float4 v = make_float4(0.f, 0.f, 0.f, 0.f);
            if (n < N) v = *(const float4*)(W + (size_t)n * K + kk + lc);
            Ws[lc + 0][lr] = v.x; Ws[lc + 1][lr] = v.y;
            Ws[lc + 2][lr] = v.z; Ws[lc + 3][lr] = v.w;
        }
        __syncthreads();
        #pragma unroll
        for (int k = 0; k < KT; ++k) {
            float a[4], w[4];
            #pragma unroll
            for (int i = 0; i < 4; ++i) a[i] = As[k][ty * 4 + i];
            #pragma unroll
            for (int j = 0; j < 4; ++j) w[j] = Ws[k][tx * 4 + j];
            #pragma unroll
            for (int i = 0; i < 4; ++i)
                #pragma unroll
                for (int j = 0; j < 4; ++j)
                    acc[i][j] = fmaf(a[i], w[j], acc[i][j]);
        }
        __syncthreads();
    }

    #pragma unroll
    for (int i = 0; i < 4; ++i) {
        int m = m0 + ty * 4 + i;
        if (m >= M) continue;
        #pragma unroll
        for (int j = 0; j < 4; ++j) {
            int n = n0 + tx * 4 + j;
            if (n >= N) continue;
            float val = acc[i][j];
            if (bias) val += bias[n];
            if (accumulate) val += C[(size_t)m * N + n];
            C[(size_t)m * N + n] = val;
        }
    }
}

// Final vocab projection: rows m = t*128+b of hseq; write out[b][t][n], masked.
__global__ __launch_bounds__(256) void gemm_out_k(
    const float* __restrict__ A, const float* __restrict__ W,
    const float* __restrict__ bias, const int* __restrict__ lengths,
    float* __restrict__ out)
{
    __shared__ float As[KT][TILE];
    __shared__ float Ws[KT][TILE];
    const int tid = threadIdx.x;
    const int tx = tid & 15, ty = tid >> 4;
    const int m0 = blockIdx.y * TILE;
    const int n0 = blockIdx.x * TILE;
    const int lr = tid >> 2;
    const int lc = (tid & 3) * 4;
    const int M = T * B, N = V, K = D;
    float acc[4][4] = {};

    for (int kk = 0; kk < K; kk += KT) {
        {
            int m = m0 + lr;
            float4 v = make_float4(0.f, 0.f, 0.f, 0.f);
            if (m < M) v = *(const float4*)(A + (size_t)m * K + kk + lc);
            As[lc + 0][lr] = v.x; As[lc + 1][lr] = v.y;
            As[lc + 2][lr] = v.z; As[lc + 3][lr] = v.w;
        }
        {
            int n = n0 + lr;
            float4 v = make_float4(0.f, 0.f, 0.f, 0.f);
            if (n < N) v = *(const float4*)(W + (size_t)n * K + kk + lc);
            Ws[lc + 0][lr] = v.x; Ws[lc + 1][lr] = v.y;
            Ws[lc + 2][lr] = v.z; Ws[lc + 3][lr] = v.w;
        }
        __syncthreads();
        #pragma unroll
        for (int k = 0; k < KT; ++k) {
            float a[4], w[4];
            #pragma unroll
            for (int i = 0; i < 4; ++i) a[i] = As[k][ty * 4 + i];
            #pragma unroll
            for (int j = 0; j < 4; ++j) w[j] = Ws[k][tx * 4 + j];
            #pragma unroll
            for (int i = 0; i < 4; ++i)
                #pragma unroll
                for (int j = 0; j < 4; ++j)
                    acc[i][j] = fmaf(a[i], w[j], acc[i][j]);
        }
        __syncthreads();
    }

    #pragma unroll
    for (int i = 0; i < 4; ++i) {
        int m = m0 + ty * 4 + i;
        if (m >= M) continue;
        int t = m >> 7, b = m & 127;
        bool mask = t < lengths[b];
        #pragma unroll
        for (int j = 0; j < 4; ++j) {
            int n = n0 + tx * 4 + j;
            if (n >= N) continue;
            float val = mask ? (acc[i][j] + bias[n]) : 0.0f;
            out[((size_t)b * T + t) * V + n] = val;
        }
    }
}

// words[b][t][:] = embed_W[captions[b][t]][:]   (t < T)
__global__ __launch_bounds__(128) void embed_k(
    const int* __restrict__ captions, const float* __restrict__ embed_W,
    float* __restrict__ words)
{
    int bt = blockIdx.x;              // b*T + t
    int b = bt / T, t = bt % T;
    int tok = captions[b * MAXLEN + t];
    const float4* src = (const float4*)(embed_W + (size_t)tok * E);
    float4* dst = (float4*)(words + (size_t)bt * E);
    dst[threadIdx.x] = src[threadIdx.x];   // 128 threads * 4 floats = 512
}

// feas0[b][v] = mean over r of visual[b][r][v]
__global__ __launch_bounds__(256) void feas0_k(
    const float* __restrict__ visual, float* __restrict__ feas0)
{
    int idx = blockIdx.x * 256 + threadIdx.x;
    if (idx >= B * VIS) return;
    int b = idx >> 11, v = idx & (VIS - 1);
    float s = 0.f;
    for (int r = 0; r < R; ++r) s += visual[((size_t)b * R + r) * VIS + v];
    feas0[idx] = s * (1.0f / R);
}

// scores[b][r] = sum_a relu(att_fea[b][r][a] + ah[b][a] + att_bias[r]) * Ww[a]
__global__ __launch_bounds__(64) void att_score_k(
    const float* __restrict__ att_fea, const float* __restrict__ ah,
    const float* __restrict__ att_bias, const float* __restrict__ Ww,
    float* __restrict__ scores)
{
    int br = blockIdx.x;
    int b = br / R, r = br % R;
    int lane = threadIdx.x;
    const float* af = att_fea + (size_t)br * ATT;
    const float* ahb = ah + (size_t)b * ATT;
    float ab = att_bias[r];
    float s = 0.f;
    for (int i = lane; i < ATT; i += 64) {
        float v = af[i] + ahb[i] + ab;
        v = fmaxf(v, 0.f);
        s = fmaf(v, Ww[i], s);
    }
    #pragma unroll
    for (int off = 32; off > 0; off >>= 1) s += __shfl_down(s, off);
    if (lane == 0) scores[br] = s;
}

// softmax over R, ctx = alpha . visual, assemble x = [feas | words_t]
__global__ __launch_bounds__(256) void softmax_ctx_k(
    const float* __restrict__ scores, const float* __restrict__ visual,
    const float* __restrict__ feas0, const float* __restrict__ words,
    float* __restrict__ x, int t)
{
    int b = blockIdx.x;
    int tid = threadIdx.x;
    __shared__ float sal[R];
    if (tid < 64) {
        float v = (tid < R) ? scores[b * R + tid] : -INFINITY;
        float m = v;
        #pragma unroll
        for (int off = 32; off > 0; off >>= 1) m = fmaxf(m, __shfl_down(m, off));
        m = __shfl(m, 0);
        float e = (tid < R) ? expf(v - m) : 0.f;
        float ssum = e;
        #pragma unroll
        for (int off = 32; off > 0; off >>= 1) ssum += __shfl_down(ssum, off);
        ssum = __shfl(ssum, 0);
        if (tid < R) sal[tid] = e / ssum;
    }
    __syncthreads();

    if (t == 0) {
        for (int v = tid; v < VIS; v += 256)
            x[(size_t)b * XDIM + v] = feas0[(size_t)b * VIS + v];
    } else {
        for (int v = tid; v < VIS; v += 256) {
            float s = 0.f;
            for (int r = 0; r < R; ++r)
                s = fmaf(sal[r], visual[((size_t)b * R + r) * VIS + v], s);
            x[(size_t)b * XDIM + v] = s;
        }
    }
    for (int e = tid; e < E; e += 256)
        x[(size_t)b * XDIM + VIS + e] = words[((size_t)b * T + t) * E + e];
}

// LSTM pointwise: gates (B,4D) -> update h,c with mask, store h into hseq[t]
__global__ __launch_bounds__(256) void lstm_k(
    const float* __restrict__ gates, float* __restrict__ h, float* __restrict__ c,
    float* __restrict__ hseq, const int* __restrict__ lengths, int t)
{
    int idx = blockIdx.x * 256 + threadIdx.x;
    if (idx >= B * D) return;
    int b = idx >> 10, d = idx & (D - 1);
    const float* g = gates + (size_t)b * G4;
    float ig = sigmoidf_(g[d]);
    float fg = sigmoidf_(g[D + d]);
    float gg = tanhf(g[2 * D + d]);
    float og = sigmoidf_(g[3 * D + d]);
    float cn = fmaf(fg, c[idx], ig * gg);
    float hn = og * tanhf(cn);
    bool mask = t < lengths[b];
    float hv = mask ? hn : h[idx];
    float cv = mask ? cn : c[idx];
    h[idx] = hv;
    c[idx] = cv;
    hseq[(size_t)t * (B * D) + idx] = hv;
}

extern "C" void kernel_launch(void* const* d_in, const int* in_sizes, int n_in,
                              void* d_out, int out_size, void* d_ws, size_t ws_size,
                              hipStream_t stream) {
    const float* visual   = (const float*)d_in[0];
    const float* joint    = (const float*)d_in[1];
    const int*   captions = (const int*)d_in[2];
    const int*   lengths  = (const int*)d_in[3];
    // d_in[4] = max_len (static = 20)
    const float* embed_W  = (const float*)d_in[5];
    const float* Wih      = (const float*)d_in[6];
    const float* bih      = (const float*)d_in[7];
    const float* Whh      = (const float*)d_in[8];
    const float* bhh      = (const float*)d_in[9];
    const float* W_init_h = (const float*)d_in[10];
    const float* b_init_h = (const float*)d_in[11];
    const float* W_init_c = (const float*)d_in[12];
    const float* b_init_c = (const float*)d_in[13];
    const float* Wv       = (const float*)d_in[14];
    const float* Wh       = (const float*)d_in[15];
    const float* att_bias = (const float*)d_in[16];
    const float* Ww       = (const float*)d_in[17];
    const float* Wout     = (const float*)d_in[18];
    const float* bout     = (const float*)d_in[19];
    float* out = (float*)d_out;

    // Workspace layout (floats)
    float* ws = (float*)d_ws;
    float* att_fea = ws;                      // B*R*ATT     = 2359296
    float* words   = att_fea + (size_t)B * R * ATT;   // B*T*E = 1245184
    float* h       = words + (size_t)B * T * E;       // B*D   = 131072
    float* c       = h + (size_t)B * D;               // B*D
    float* hseq    = c + (size_t)B * D;               // T*B*D = 2490368
    float* ah      = hseq + (size_t)T * B * D;        // B*ATT = 65536
    float* scores  = ah + (size_t)B * ATT;            // B*R   = 4608
    float* xbuf    = scores + (size_t)B * R;          // B*XDIM= 327680
    float* gates   = xbuf + (size_t)B * XDIM;         // B*4D  = 524288
    float* feas0   = gates + (size_t)B * G4;          // B*VIS = 262144

    // One-shot precompute
    embed_k<<<B * T, 128, 0, stream>>>(captions, embed_W, words);
    feas0_k<<<(B * VIS + 255) / 256, 256, 0, stream>>>(visual, feas0);
    gemm_nt<<<dim3(D / TILE, B / TILE), 256, 0, stream>>>(joint, W_init_h, b_init_h, h, B, D, MM, 0);
    gemm_nt<<<dim3(D / TILE, B / TILE), 256, 0, stream>>>(joint, W_init_c, b_init_c, c, B, D, MM, 0);
    gemm_nt<<<dim3(ATT / TILE, (B * R) / TILE), 256, 0, stream>>>(visual, Wv, nullptr, att_fea, B * R, ATT, VIS, 0);

    // Recurrence
    for (int t = 0; t < T; ++t) {
        gemm_nt<<<dim3(ATT / TILE, B / TILE), 256, 0, stream>>>(h, Wh, nullptr, ah, B, ATT, D, 0);
        att_score_k<<<B * R, 64, 0, stream>>>(att_fea, ah, att_bias, Ww, scores);
        softmax_ctx_k<<<B, 256, 0, stream>>>(scores, visual, feas0, words, xbuf, t);
        gemm_nt<<<dim3(G4 / TILE, B / TILE), 256, 0, stream>>>(xbuf, Wih, bih, gates, B, G4, XDIM, 0);
        gemm_nt<<<dim3(G4 / TILE, B / TILE), 256, 0, stream>>>(h, Whh, bhh, gates, B, G4, D, 1);
        lstm_k<<<(B * D + 255) / 256, 256, 0, stream>>>(gates, h, c, hseq, lengths, t);
    }

    // Deferred vocab projection with mask
    gemm_out_k<<<dim3((V + TILE - 1) / TILE, (T * B) / TILE), 256, 0, stream>>>(
        hseq, Wout, bout, lengths, out);
}

// Round 2
// 2318.859 us; speedup vs baseline: 3.1053x; 3.1053x over previous
//
#include <hip/hip_runtime.h>
#include <math.h>

// Problem constants (fixed by reference)
#define B 128
#define R 36
#define VIS 2048
#define MM 1024
#define E 512
#define ATT 512
#define D 1024
#define V 10000
#define MAXLEN 20
#define T 19          // MAXLEN - 1
#define G4 4096       // 4*D

typedef unsigned short bf16_t;
typedef __attribute__((ext_vector_type(8))) short short8;
typedef __attribute__((ext_vector_type(4))) float f32x4;
typedef __attribute__((ext_vector_type(4))) unsigned short ushort4v;

__device__ __forceinline__ bf16_t f2bf(float f) {
    unsigned u = __float_as_uint(f);
    u += 0x7fff + ((u >> 16) & 1);   // round-to-nearest-even
    return (bf16_t)(u >> 16);
}
__device__ __forceinline__ float bf2f(bf16_t b) {
    return __uint_as_float(((unsigned)b) << 16);
}
__device__ __forceinline__ float sigmoidf_(float x) { return 1.0f / (1.0f + expf(-x)); }

// ---------------------------------------------------------------------------
// Generic bf16 MFMA GEMM: C[M,N] = [A1|A2][M,K1+K2] @ [W1|W2][N,K1+K2]^T
// MODE 0: C = acc (+bias1)            (C fp32, ldc)
// MODE 1: C = acc + bias1 + bias2 + add[m*ldc+n]   (gates epilogue)
// MODE 2: out-projection: m = t*B+b; out[(b*T+t)*V+n] = mask ? acc+bias1 : 0
// ---------------------------------------------------------------------------
template<int BM, int BN, int MODE>
__global__ __launch_bounds__(256) void mfma_gemm(
    const bf16_t* __restrict__ A1, int K1,
    const bf16_t* __restrict__ A2, int K2,
    const bf16_t* __restrict__ W1, const bf16_t* __restrict__ W2,
    const float* __restrict__ bias1, const float* __restrict__ bias2,
    const float* __restrict__ add, const int* __restrict__ lengths,
    float* __restrict__ C, int M, int N, int ldc)
{
    constexpr int WM = BM / 2, WN = BN / 2;
    constexpr int FM = WM / 16, FN = WN / 16;
    __shared__ __align__(16) bf16_t As[BM][40];   // 32 k + 8 pad (2-way alias only)
    __shared__ __align__(16) bf16_t Ws[BN][40];

    const int tid = threadIdx.x;
    const int wave = tid >> 6, lane = tid & 63;
    const int wm = wave >> 1, wn = wave & 1;
    const int quad = lane >> 4, l16 = lane & 15;
    const int m0 = blockIdx.y * BM, n0 = blockIdx.x * BN;

    f32x4 acc[FM][FN];
    #pragma unroll
    for (int i = 0; i < FM; ++i)
        #pragma unroll
        for (int j = 0; j < FN; ++j)
            acc[i][j] = (f32x4){0.f, 0.f, 0.f, 0.f};

    const int ktot = (K1 + K2) >> 5;
    for (int kt = 0; kt < ktot; ++kt) {
        const bf16_t* A; const bf16_t* W; int koff, lda;
        if (kt * 32 < K1) { A = A1; W = W1; koff = kt * 32;      lda = K1; }
        else              { A = A2; W = W2; koff = kt * 32 - K1; lda = K2; }

        #pragma unroll
        for (int i = 0; i < (BM * 4) / 256; ++i) {
            int c = tid + i * 256;
            int row = c >> 2, seg = c & 3;
            int m = m0 + row; if (m >= M) m = M - 1;
            short8 v = *(const short8*)(A + (size_t)m * lda + koff + seg * 8);
            *(short8*)&As[row][seg * 8] = v;
        }
        #pragma unroll
        for (int i = 0; i < (BN * 4) / 256; ++i) {
            int c = tid + i * 256;
            int row = c >> 2, seg = c & 3;
            int n = n0 + row; if (n >= N) n = N - 1;
            short8 v = *(const short8*)(W + (size_t)n * lda + koff + seg * 8);
            *(short8*)&Ws[row][seg * 8] = v;
        }
        __syncthreads();

        short8 af[FM], bfr[FN];
        #pragma unroll
        for (int fm = 0; fm < FM; ++fm)
            af[fm] = *(const short8*)&As[wm * WM + fm * 16 + l16][quad * 8];
        #pragma unroll
        for (int fn = 0; fn < FN; ++fn)
            bfr[fn] = *(const short8*)&Ws[wn * WN + fn * 16 + l16][quad * 8];
        #pragma unroll
        for (int fm = 0; fm < FM; ++fm)
            #pragma unroll
            for (int fn = 0; fn < FN; ++fn)
                acc[fm][fn] = __builtin_amdgcn_mfma_f32_16x16x32_bf16(
                    af[fm], bfr[fn], acc[fm][fn], 0, 0, 0);
        __syncthreads();
    }

    #pragma unroll
    for (int fm = 0; fm < FM; ++fm)
        #pragma unroll
        for (int fn = 0; fn < FN; ++fn)
            #pragma unroll
            for (int r = 0; r < 4; ++r) {
                int m = m0 + wm * WM + fm * 16 + quad * 4 + r;
                int n = n0 + wn * WN + fn * 16 + l16;
                if (m >= M || n >= N) continue;
                float v = acc[fm][fn][r];
                if (MODE == 0) {
                    if (bias1) v += bias1[n];
                    C[(size_t)m * ldc + n] = v;
                } else if (MODE == 1) {
                    v += bias1[n] + bias2[n] + add[(size_t)m * ldc + n];
                    C[(size_t)m * ldc + n] = v;
                } else {
                    int t = m >> 7, b = m & 127;
                    v = (t < lengths[b]) ? (v + bias1[n]) : 0.f;
                    C[((size_t)b * T + t) * V + n] = v;
                }
            }
}

// fp32 tile GEMM kept for the tiny one-shot h0/c0 init:  C = A@W^T + bias
#define TILE 64
#define KT 16
__global__ __launch_bounds__(256) void gemm_nt(
    const float* __restrict__ A, const float* __restrict__ W,
    const float* __restrict__ bias, float* __restrict__ C,
    int M, int N, int K)
{
    __shared__ float Asf[KT][TILE];
    __shared__ float Wsf[KT][TILE];
    const int tid = threadIdx.x;
    const int tx = tid & 15, ty = tid >> 4;
    const int m0 = blockIdx.y * TILE;
    const int n0 = blockIdx.x * TILE;
    const int lr = tid >> 2;
    const int lc = (tid & 3) * 4;
    float acc[4][4] = {};
    for (int kk = 0; kk < K; kk += KT) {
        {
            int m = m0 + lr;
            float4 v = make_float4(0.f, 0.f, 0.f, 0.f);
            if (m < M) v = *(const float4*)(A + (size_t)m * K + kk + lc);
            Asf[lc + 0][lr] = v.x; Asf[lc + 1][lr] = v.y;
            Asf[lc + 2][lr] = v.z; Asf[lc + 3][lr] = v.w;
        }
        {
            int n = n0 + lr;
            float4 v = make_float4(0.f, 0.f, 0.f, 0.f);
            if (n < N) v = *(const float4*)(W + (size_t)n * K + kk + lc);
            Wsf[lc + 0][lr] = v.x; Wsf[lc + 1][lr] = v.y;
            Wsf[lc + 2][lr] = v.z; Wsf[lc + 3][lr] = v.w;
        }
        __syncthreads();
        #pragma unroll
        for (int k = 0; k < KT; ++k) {
            float a[4], w[4];
            #pragma unroll
            for (int i = 0; i < 4; ++i) a[i] = Asf[k][ty * 4 + i];
            #pragma unroll
            for (int j = 0; j < 4; ++j) w[j] = Wsf[k][tx * 4 + j];
            #pragma unroll
            for (int i = 0; i < 4; ++i)
                #pragma unroll
                for (int j = 0; j < 4; ++j)
                    acc[i][j] = fmaf(a[i], w[j], acc[i][j]);
        }
        __syncthreads();
    }
    #pragma unroll
    for (int i = 0; i < 4; ++i) {
        int m = m0 + ty * 4 + i;
        if (m >= M) continue;
        #pragma unroll
        for (int j = 0; j < 4; ++j) {
            int n = n0 + tx * 4 + j;
            if (n >= N) continue;
            C[(size_t)m * N + n] = acc[i][j] + (bias ? bias[n] : 0.f);
        }
    }
}

// Strided fp32 -> bf16 cast: dst[r*cols+c] = bf16(src[r*ld+c])
__global__ __launch_bounds__(256) void cast_bf16_k(
    const float* __restrict__ src, bf16_t* __restrict__ dst,
    int rows, int cols, int ld)
{
    int idx = blockIdx.x * 256 + threadIdx.x;
    int total = rows * (cols >> 2);
    if (idx >= total) return;
    int cq = cols >> 2;
    int r = idx / cq, c4 = (idx - r * cq) * 4;
    float4 v = *(const float4*)(src + (size_t)r * ld + c4);
    ushort4v o = { f2bf(v.x), f2bf(v.y), f2bf(v.z), f2bf(v.w) };
    *(ushort4v*)(dst + (size_t)r * cols + c4) = o;
}

// words_bf[(t*B+b)*E + :] = bf16(embed_W[captions[b][t]][:])
__global__ __launch_bounds__(128) void embed_k(
    const int* __restrict__ captions, const float* __restrict__ embed_W,
    bf16_t* __restrict__ words_bf)
{
    int bt = blockIdx.x;              // b*T + t
    int b = bt / T, t = bt - b * T;
    int tok = captions[b * MAXLEN + t];
    int i = threadIdx.x * 4;
    float4 v = *(const float4*)(embed_W + (size_t)tok * E + i);
    ushort4v o = { f2bf(v.x), f2bf(v.y), f2bf(v.z), f2bf(v.w) };
    *(ushort4v*)(words_bf + ((size_t)t * B + b) * E + i) = o;
}

// feas0_bf[b][v] = bf16(mean_r visual[b][r][v])
__global__ __launch_bounds__(256) void feas0_k(
    const float* __restrict__ visual, bf16_t* __restrict__ feas0_bf)
{
    int idx = blockIdx.x * 256 + threadIdx.x;
    if (idx >= B * VIS) return;
    int b = idx >> 11, v = idx & (VIS - 1);
    float s = 0.f;
    for (int r = 0; r < R; ++r) s += visual[((size_t)b * R + r) * VIS + v];
    feas0_bf[idx] = f2bf(s * (1.0f / R));
}

// Fused per-step attention: ah = h@Wh^T, scores, softmax, ctx (bf16 out)
__global__ __launch_bounds__(256) void fused_att(
    const float* __restrict__ h, const bf16_t* __restrict__ Wh_bf,
    const float* __restrict__ att_fea, const float* __restrict__ att_bias,
    const float* __restrict__ Ww, const bf16_t* __restrict__ visual_bf,
    bf16_t* __restrict__ ctx_bf)
{
    int b = blockIdx.x, tid = threadIdx.x;
    __shared__ float hs[D];
    __shared__ float ah_s[ATT];
    __shared__ float sc_s[R];
    __shared__ float alpha_s[R];

    ((float4*)hs)[tid] = ((const float4*)(h + (size_t)b * D))[tid];  // 256*4 = 1024
    __syncthreads();

    for (int a = tid; a < ATT; a += 256) {
        const bf16_t* wrow = Wh_bf + (size_t)a * D;
        float s = 0.f;
        for (int k = 0; k < D; k += 8) {
            short8 wv = *(const short8*)(wrow + k);
            #pragma unroll
            for (int j = 0; j < 8; ++j)
                s = fmaf(bf2f((bf16_t)wv[j]), hs[k + j], s);
        }
        ah_s[a] = s;
    }
    __syncthreads();

    int wave = tid >> 6, lane = tid & 63;
    for (int r = wave; r < R; r += 4) {
        float ab = att_bias[r];
        const float* af = att_fea + ((size_t)b * R + r) * ATT;
        float s = 0.f;
        for (int a = lane; a < ATT; a += 64) {
            float v = af[a] + ah_s[a] + ab;
            s = fmaf(fmaxf(v, 0.f), Ww[a], s);
        }
        #pragma unroll
        for (int off = 32; off; off >>= 1) s += __shfl_down(s, off);
        if (lane == 0) sc_s[r] = s;
    }
    __syncthreads();

    if (tid < 64) {
        float v = (tid < R) ? sc_s[tid] : -INFINITY;
        float m = v;
        #pragma unroll
        for (int off = 32; off; off >>= 1) m = fmaxf(m, __shfl_down(m, off));
        m = __shfl(m, 0);
        float e = (tid < R) ? expf(v - m) : 0.f;
        float ss = e;
        #pragma unroll
        for (int off = 32; off; off >>= 1) ss += __shfl_down(ss, off);
        ss = __shfl(ss, 0);
        if (tid < R) alpha_s[tid] = e / ss;
    }
    __syncthreads();

    {
        int v0 = tid * 8;     // 256 * 8 = 2048
        float acc[8] = {};
        for (int r = 0; r < R; ++r) {
            float al = alpha_s[r];
            short8 vv = *(const short8*)(visual_bf + ((size_t)b * R + r) * VIS + v0);
            #pragma unroll
            for (int j = 0; j < 8; ++j)
                acc[j] = fmaf(al, bf2f((bf16_t)vv[j]), acc[j]);
        }
        short8 o;
        #pragma unroll
        for (int j = 0; j < 8; ++j) o[j] = (short)f2bf(acc[j]);
        *(short8*)(ctx_bf + (size_t)b * VIS + v0) = o;
    }
}

// LSTM pointwise; writes fp32 h (for att), bf16 h (for gates), bf16 hseq[t]
__global__ __launch_bounds__(256) void lstm_k(
    const float* __restrict__ gates, float* __restrict__ h, float* __restrict__ c,
    bf16_t* __restrict__ h_bf, bf16_t* __restrict__ hseq_bf,
    const int* __restrict__ lengths, int t)
{
    int idx = blockIdx.x * 256 + threadIdx.x;
    if (idx >= B * D) return;
    int b = idx >> 10;
    int d = idx & (D - 1);
    const float* g = gates + (size_t)b * G4;
    float ig = sigmoidf_(g[d]);
    float fg = sigmoidf_(g[D + d]);
    float gg = tanhf(g[2 * D + d]);
    float og = sigmoidf_(g[3 * D + d]);
    float cn = fmaf(fg, c[idx], ig * gg);
    float hn = og * tanhf(cn);
    bool mask = t < lengths[b];
    float hv = mask ? hn : h[idx];
    float cv = mask ? cn : c[idx];
    h[idx] = hv;
    c[idx] = cv;
    h_bf[idx] = f2bf(hv);
    hseq_bf[((size_t)t * B + b) * D + d] = f2bf(hv);
}

extern "C" void kernel_launch(void* const* d_in, const int* in_sizes, int n_in,
                              void* d_out, int out_size, void* d_ws, size_t ws_size,
                              hipStream_t stream) {
    const float* visual   = (const float*)d_in[0];
    const float* joint    = (const float*)d_in[1];
    const int*   captions = (const int*)d_in[2];
    const int*   lengths  = (const int*)d_in[3];
    const float* embed_W  = (const float*)d_in[5];
    const float* Wih      = (const float*)d_in[6];
    const float* bih      = (const float*)d_in[7];
    const float* Whh      = (const float*)d_in[8];
    const float* bhh      = (const float*)d_in[9];
    const float* W_init_h = (const float*)d_in[10];
    const float* b_init_h = (const float*)d_in[11];
    const float* W_init_c = (const float*)d_in[12];
    const float* b_init_c = (const float*)d_in[13];
    const float* Wv       = (const float*)d_in[14];
    const float* Wh       = (const float*)d_in[15];
    const float* att_bias = (const float*)d_in[16];
    const float* Ww       = (const float*)d_in[17];
    const float* Wout     = (const float*)d_in[18];
    const float* bout     = (const float*)d_in[19];
    float* out = (float*)d_out;

    // ---- workspace carve-up (16B-aligned segments) ----
    char* cur = (char*)d_ws;
    auto alloc = [&](size_t bytes) { char* p = cur; cur += (bytes + 15) & ~size_t(15); return p; };
    float*  att_fea  = (float*)alloc((size_t)B * R * ATT * 4);       // 9.44 MB
    float*  wordsW   = (float*)alloc((size_t)T * B * G4 * 4);        // 39.8 MB
    float*  gates    = (float*)alloc((size_t)B * G4 * 4);            // 2.1 MB
    float*  h        = (float*)alloc((size_t)B * D * 4);
    float*  c        = (float*)alloc((size_t)B * D * 4);
    bf16_t* words_bf = (bf16_t*)alloc((size_t)T * B * E * 2);        // 2.5 MB
    bf16_t* h_bf     = (bf16_t*)alloc((size_t)B * D * 2);
    bf16_t* hseq_bf  = (bf16_t*)alloc((size_t)T * B * D * 2);        // 5 MB
    bf16_t* ctx_bf   = (bf16_t*)alloc((size_t)B * VIS * 2);
    bf16_t* feas0_bf = (bf16_t*)alloc((size_t)B * VIS * 2);
    bf16_t* visual_bf= (bf16_t*)alloc((size_t)B * R * VIS * 2);      // 18.9 MB
    bf16_t* Wv_bf    = (bf16_t*)alloc((size_t)ATT * VIS * 2);
    bf16_t* Wh_bf    = (bf16_t*)alloc((size_t)ATT * D * 2);
    bf16_t* Whh_bf   = (bf16_t*)alloc((size_t)G4 * D * 2);           // 8.4 MB
    bf16_t* Wih_v_bf = (bf16_t*)alloc((size_t)G4 * VIS * 2);         // 16.8 MB
    bf16_t* Wih_w_bf = (bf16_t*)alloc((size_t)G4 * E * 2);           // 4.2 MB
    bf16_t* Wout_bf  = (bf16_t*)alloc((size_t)V * D * 2);            // 20.5 MB

    // ---- one-shot: casts ----
    auto cast = [&](const float* s, bf16_t* dst, int rows, int cols, int ld) {
        int total = rows * (cols >> 2);
        cast_bf16_k<<<(total + 255) / 256, 256, 0, stream>>>(s, dst, rows, cols, ld);
    };
    cast(visual, visual_bf, 1, B * R * VIS, B * R * VIS);
    cast(Wv,  Wv_bf,  ATT, VIS, VIS);
    cast(Wh,  Wh_bf,  ATT, D, D);
    cast(Whh, Whh_bf, G4, D, D);
    cast(Wih, Wih_v_bf, G4, VIS, VIS + E);            // Wih[:, :VIS]
    cast(Wih + VIS, Wih_w_bf, G4, E, VIS + E);        // Wih[:, VIS:]
    cast(Wout, Wout_bf, V, D, D);

    embed_k<<<B * T, 128, 0, stream>>>(captions, embed_W, words_bf);
    feas0_k<<<(B * VIS + 255) / 256, 256, 0, stream>>>(visual, feas0_bf);

    // h0/c0 (fp32 — tiny, keeps recurrence seed accurate)
    gemm_nt<<<dim3(D / TILE, B / TILE), 256, 0, stream>>>(joint, W_init_h, b_init_h, h, B, D, MM);
    gemm_nt<<<dim3(D / TILE, B / TILE), 256, 0, stream>>>(joint, W_init_c, b_init_c, c, B, D, MM);
    cast(h, h_bf, 1, B * D, B * D);

    // att_fea = visual @ Wv^T  (fp32 out, consumed by fused_att)
    mfma_gemm<128, 128, 0><<<dim3(ATT / 128, (B * R) / 128), 256, 0, stream>>>(
        visual_bf, VIS, nullptr, 0, Wv_bf, nullptr, nullptr, nullptr, nullptr, nullptr,
        att_fea, B * R, ATT, ATT);

    // wordsW[t*B+b] = words @ Wih_w^T   (all steps at once)
    mfma_gemm<128, 128, 0><<<dim3(G4 / 128, (T * B) / 128), 256, 0, stream>>>(
        words_bf, E, nullptr, 0, Wih_w_bf, nullptr, nullptr, nullptr, nullptr, nullptr,
        wordsW, T * B, G4, G4);

    // ---- recurrence ----
    for (int t = 0; t < T; ++t) {
        const bf16_t* A1 = feas0_bf;
        if (t > 0) {
            fused_att<<<B, 256, 0, stream>>>(h, Wh_bf, att_fea, att_bias, Ww, visual_bf, ctx_bf);
            A1 = ctx_bf;
        }
        mfma_gemm<64, 64, 1><<<dim3(G4 / 64, B / 64), 256, 0, stream>>>(
            A1, VIS, h_bf, D, Wih_v_bf, Whh_bf, bih, bhh,
            wordsW + (size_t)t * B * G4, nullptr, gates, B, G4, G4);
        lstm_k<<<(B * D + 255) / 256, 256, 0, stream>>>(gates, h, c, h_bf, hseq_bf, lengths, t);
    }

    // ---- deferred vocab projection (bf16 MFMA, mask in epilogue) ----
    mfma_gemm<128, 128, 2><<<dim3((V + 127) / 128, (T * B) / 128), 256, 0, stream>>>(
        hseq_bf, D, nullptr, 0, Wout_bf, nullptr, bout, nullptr, nullptr, lengths,
        out, T * B, V, V);
}

// Round 5
// 2132.822 us; speedup vs baseline: 3.3761x; 1.0872x over previous
//
#include <hip/hip_runtime.h>
#include <math.h>

// Problem constants (fixed by reference)
#define B 128
#define R 36
#define VIS 2048
#define MM 1024
#define E 512
#define ATT 512
#define D 1024
#define V 10000
#define MAXLEN 20
#define T 19          // MAXLEN - 1
#define G4 4096       // 4*D

typedef unsigned short bf16_t;
typedef __attribute__((ext_vector_type(8))) short short8;
typedef __attribute__((ext_vector_type(4))) float f32x4;
typedef __attribute__((ext_vector_type(4))) unsigned short ushort4v;

__device__ __forceinline__ bf16_t f2bf(float f) {
    unsigned u = __float_as_uint(f);
    u += 0x7fff + ((u >> 16) & 1);   // round-to-nearest-even
    return (bf16_t)(u >> 16);
}
__device__ __forceinline__ float bf2f(bf16_t b) {
    return __uint_as_float(((unsigned)b) << 16);
}
__device__ __forceinline__ float sigmoidf_(float x) { return 1.0f / (1.0f + expf(-x)); }

// Async global->LDS, 16B per lane. LDS dest = wave-uniform base + lane*16.
__device__ __forceinline__ void stage16(const bf16_t* g, bf16_t* lds_wave_base, int lane) {
#if defined(__has_builtin) && __has_builtin(__builtin_amdgcn_global_load_lds)
    __builtin_amdgcn_global_load_lds(
        (const __attribute__((address_space(1))) void*)g,
        (__attribute__((address_space(3))) void*)lds_wave_base, 16, 0, 0);
#else
    *(short8*)(lds_wave_base + lane * 8) = *(const short8*)g;
#endif
}

// ---------------------------------------------------------------------------
// 128x128-tile bf16 MFMA GEMM, m97 structure (global_load_lds, contiguous k-32
// rows in LDS, 4 waves in 64x64 quadrants, FM=FN=4).
// MODE 0: C[m*ldc+n] = acc (+bias)
// MODE 2: m = t*B+b; out[(b*T+t)*V+n] = (t<len[b]) ? acc+bias : 0
// ---------------------------------------------------------------------------
template<int MODE>
__global__ __launch_bounds__(256) void mfma_gemm_lds(
    const bf16_t* __restrict__ A, const bf16_t* __restrict__ W,
    const float* __restrict__ bias, const int* __restrict__ lengths,
    float* __restrict__ C, int M, int N, int K, int ldc)
{
    __shared__ __align__(16) bf16_t As[128 * 32];
    __shared__ __align__(16) bf16_t Ws[128 * 32];
    const int tid = threadIdx.x;
    const int wave = tid >> 6, lane = tid & 63;
    const int wm = wave >> 1, wn = wave & 1;
    const int quad = lane >> 4, l16 = lane & 15;
    const int m0 = blockIdx.y * 128, n0 = blockIdx.x * 128;

    f32x4 acc[4][4];
    #pragma unroll
    for (int i = 0; i < 4; ++i)
        #pragma unroll
        for (int j = 0; j < 4; ++j)
            acc[i][j] = (f32x4){0.f, 0.f, 0.f, 0.f};

    for (int kk = 0; kk < K; kk += 32) {
        #pragma unroll
        for (int i = 0; i < 2; ++i) {
            int c = tid + i * 256;          // chunk 0..511
            int row = c >> 2, seg = c & 3;
            int m = m0 + row; if (m >= M) m = M - 1;
            stage16(A + (size_t)m * K + kk + seg * 8, &As[(i * 256 + wave * 64) * 8], lane);
            int n = n0 + row; if (n >= N) n = N - 1;
            stage16(W + (size_t)n * K + kk + seg * 8, &Ws[(i * 256 + wave * 64) * 8], lane);
        }
        __syncthreads();
        short8 af[4], bfr[4];
        #pragma unroll
        for (int fm = 0; fm < 4; ++fm)
            af[fm] = *(const short8*)&As[(wm * 64 + fm * 16 + l16) * 32 + quad * 8];
        #pragma unroll
        for (int fn = 0; fn < 4; ++fn)
            bfr[fn] = *(const short8*)&Ws[(wn * 64 + fn * 16 + l16) * 32 + quad * 8];
        #pragma unroll
        for (int fm = 0; fm < 4; ++fm)
            #pragma unroll
            for (int fn = 0; fn < 4; ++fn)
                acc[fm][fn] = __builtin_amdgcn_mfma_f32_16x16x32_bf16(
                    af[fm], bfr[fn], acc[fm][fn], 0, 0, 0);
        __syncthreads();
    }

    #pragma unroll
    for (int fm = 0; fm < 4; ++fm) {
        #pragma unroll
        for (int fn = 0; fn < 4; ++fn) {
            #pragma unroll
            for (int r = 0; r < 4; ++r) {
                int m = m0 + wm * 64 + fm * 16 + quad * 4 + r;
                int n = n0 + wn * 64 + fn * 16 + l16;
                if (m >= M || n >= N) continue;
                float v = acc[fm][fn][r];
                if (MODE == 0) {
                    if (bias) v += bias[n];
                    C[(size_t)m * ldc + n] = v;
                } else {
                    int t = m >> 7, b = m & 127;
                    v = (t < lengths[b]) ? (v + bias[n]) : 0.f;
                    C[((size_t)b * T + t) * V + n] = v;
                }
            }
        }
    }
}

// ---------------------------------------------------------------------------
// Fused per-step gates GEMM + LSTM pointwise.
// Block (blockIdx.x = d-tile of 8, blockIdx.y = m-tile of 64) computes the
// 32 gathered gate columns {g*D + d0+r : g=0..3, r=0..7} for 64 batch rows:
// gates = [ctx|h] @ [Wih_v|Whh]^T (+bih+bhh+wordsW[t]), then LSTM update.
// h is PING-PONG buffered: h_in (step t-1) and h_out (step t) are DISTINCT
// buffers — every block reads all of h_in while writing its slice of h_out;
// same-buffer update races across blocks (R3/R4 bug).
// ---------------------------------------------------------------------------
__global__ __launch_bounds__(256) void gates_lstm(
    const bf16_t* __restrict__ A1,      // ctx_bf or feas0_bf  (B x VIS)
    const bf16_t* __restrict__ h_in,    // B x D bf16 (step t-1; read-only here)
    const bf16_t* __restrict__ Wihv,    // G4 x VIS
    const bf16_t* __restrict__ Whh,     // G4 x D
    const float* __restrict__ bih, const float* __restrict__ bhh,
    const float* __restrict__ wordsW,   // (t*B+m)*G4
    const int* __restrict__ lengths,
    float* __restrict__ c_st,           // B x D fp32 (in/out, exclusive per (m,d))
    float* __restrict__ h_f32,          // B x D fp32 (in/out, for attention)
    bf16_t* __restrict__ h_out,         // B x D bf16 (step t; write-only here)
    bf16_t* __restrict__ hseq,          // (t*B+m)*D
    int t)
{
    __shared__ __align__(16) bf16_t As[64 * 32];
    __shared__ __align__(16) bf16_t Ws[32 * 32];
    const int tid = threadIdx.x;
    const int wave = tid >> 6, lane = tid & 63;
    const int quad = lane >> 4, l16 = lane & 15;
    const int d0 = blockIdx.x * 8;
    const int m0 = blockIdx.y * 64;

    f32x4 acc0 = (f32x4){0.f, 0.f, 0.f, 0.f};
    f32x4 acc1 = (f32x4){0.f, 0.f, 0.f, 0.f};

    const int arow = tid >> 2, aseg = tid & 3;   // A chunk (256 = 64 rows x 4 segs)
    const int wrr = tid >> 2, wseg = tid & 3;    // W chunk (128 = 32 rows x 4 segs)
    const int wg = wrr >> 3, wr = wrr & 7;
    const int wrow_v = wg * D + d0 + wr;         // gathered weight row

    for (int kt = 0; kt < 96; ++kt) {
        const bf16_t* Asrc; const bf16_t* Wsrc; int koff, lda;
        if (kt < 64) { Asrc = A1;   Wsrc = Wihv; koff = kt * 32;        lda = VIS; }
        else         { Asrc = h_in; Wsrc = Whh;  koff = (kt - 64) * 32; lda = D;   }

        stage16(Asrc + (size_t)(m0 + arow) * lda + koff + aseg * 8, &As[wave * 64 * 8], lane);
        if (wave < 2)
            stage16(Wsrc + (size_t)wrow_v * lda + koff + wseg * 8, &Ws[wave * 64 * 8], lane);
        __syncthreads();

        short8 af = *(const short8*)&As[(wave * 16 + l16) * 32 + quad * 8];
        short8 b0 = *(const short8*)&Ws[(l16) * 32 + quad * 8];
        short8 b1 = *(const short8*)&Ws[(16 + l16) * 32 + quad * 8];
        acc0 = __builtin_amdgcn_mfma_f32_16x16x32_bf16(af, b0, acc0, 0, 0, 0);
        acc1 = __builtin_amdgcn_mfma_f32_16x16x32_bf16(af, b1, acc1, 0, 0, 0);
        __syncthreads();
    }

    // Epilogue: local col fn*16+l16 = gathered row rr -> gate rr>>3, d-offset rr&7
    const int d = d0 + (l16 & 7);
    const int gsel = l16 >> 3;               // 0: holds gates {0,2}=(i,g); 1: {1,3}=(f,o)
    const int col0 = gsel * D + d;
    const int col1 = (2 + gsel) * D + d;
    const float bia0 = bih[col0] + bhh[col0];
    const float bia1 = bih[col1] + bhh[col1];

    #pragma unroll
    for (int r = 0; r < 4; ++r) {
        int m = m0 + wave * 16 + quad * 4 + r;
        size_t wb = ((size_t)t * B + m) * G4;
        float v0 = acc0[r] + bia0 + wordsW[wb + col0];
        float v1 = acc1[r] + bia1 + wordsW[wb + col1];
        float w0 = __shfl_xor(v0, 8);
        float w1 = __shfl_xor(v1, 8);
        float iv, fv, gv, ov;
        if (gsel == 0) { iv = v0; gv = v1; fv = w0; ov = w1; }
        else           { fv = v0; ov = v1; iv = w0; gv = w1; }
        float ig = sigmoidf_(iv), fg = sigmoidf_(fv);
        float gg = tanhf(gv),     og = sigmoidf_(ov);
        size_t off = (size_t)m * D + d;
        if (gsel == 0) {
            float c_old = c_st[off];
            float h_old = h_f32[off];
            float cn = fmaf(fg, c_old, ig * gg);
            float hn = og * tanhf(cn);
            bool msk = t < lengths[m];
            float cv = msk ? cn : c_old;
            float hv = msk ? hn : h_old;
            c_st[off] = cv;
            h_f32[off] = hv;
            bf16_t hb = f2bf(hv);
            h_out[off] = hb;
            hseq[((size_t)t * B + m) * D + d] = hb;
        }
    }
}

// fp32 tile GEMM for the tiny one-shot h0/c0 init:  C = A@W^T + bias
#define TILE 64
#define KT 16
__global__ __launch_bounds__(256) void gemm_nt(
    const float* __restrict__ A, const float* __restrict__ W,
    const float* __restrict__ bias, float* __restrict__ C,
    int M, int N, int K)
{
    __shared__ float Asf[KT][TILE];
    __shared__ float Wsf[KT][TILE];
    const int tid = threadIdx.x;
    const int tx = tid & 15, ty = tid >> 4;
    const int m0 = blockIdx.y * TILE;
    const int n0 = blockIdx.x * TILE;
    const int lr = tid >> 2;
    const int lc = (tid & 3) * 4;
    float acc[4][4] = {};
    for (int kk = 0; kk < K; kk += KT) {
        {
            int m = m0 + lr;
            float4 v = make_float4(0.f, 0.f, 0.f, 0.f);
            if (m < M) v = *(const float4*)(A + (size_t)m * K + kk + lc);
            Asf[lc + 0][lr] = v.x; Asf[lc + 1][lr] = v.y;
            Asf[lc + 2][lr] = v.z; Asf[lc + 3][lr] = v.w;
        }
        {
            int n = n0 + lr;
            float4 v = make_float4(0.f, 0.f, 0.f, 0.f);
            if (n < N) v = *(const float4*)(W + (size_t)n * K + kk + lc);
            Wsf[lc + 0][lr] = v.x; Wsf[lc + 1][lr] = v.y;
            Wsf[lc + 2][lr] = v.z; Wsf[lc + 3][lr] = v.w;
        }
        __syncthreads();
        #pragma unroll
        for (int k = 0; k < KT; ++k) {
            float a[4], w[4];
            #pragma unroll
            for (int i = 0; i < 4; ++i) a[i] = Asf[k][ty * 4 + i];
            #pragma unroll
            for (int j = 0; j < 4; ++j) w[j] = Wsf[k][tx * 4 + j];
            #pragma unroll
            for (int i = 0; i < 4; ++i)
                #pragma unroll
                for (int j = 0; j < 4; ++j)
                    acc[i][j] = fmaf(a[i], w[j], acc[i][j]);
        }
        __syncthreads();
    }
    #pragma unroll
    for (int i = 0; i < 4; ++i) {
        int m = m0 + ty * 4 + i;
        if (m >= M) continue;
        #pragma unroll
        for (int j = 0; j < 4; ++j) {
            int n = n0 + tx * 4 + j;
            if (n >= N) continue;
            C[(size_t)m * N + n] = acc[i][j] + (bias ? bias[n] : 0.f);
        }
    }
}

// Strided fp32 -> bf16 cast
__global__ __launch_bounds__(256) void cast_bf16_k(
    const float* __restrict__ src, bf16_t* __restrict__ dst,
    int rows, int cols, int ld)
{
    int idx = blockIdx.x * 256 + threadIdx.x;
    int total = rows * (cols >> 2);
    if (idx >= total) return;
    int cq = cols >> 2;
    int r = idx / cq, c4 = (idx - r * cq) * 4;
    float4 v = *(const float4*)(src + (size_t)r * ld + c4);
    ushort4v o = { f2bf(v.x), f2bf(v.y), f2bf(v.z), f2bf(v.w) };
    *(ushort4v*)(dst + (size_t)r * cols + c4) = o;
}

// words_bf[(t*B+b)*E + :] = bf16(embed_W[captions[b][t]][:])
__global__ __launch_bounds__(128) void embed_k(
    const int* __restrict__ captions, const float* __restrict__ embed_W,
    bf16_t* __restrict__ words_bf)
{
    int bt = blockIdx.x;
    int b = bt / T, t = bt - b * T;
    int tok = captions[b * MAXLEN + t];
    int i = threadIdx.x * 4;
    float4 v = *(const float4*)(embed_W + (size_t)tok * E + i);
    ushort4v o = { f2bf(v.x), f2bf(v.y), f2bf(v.z), f2bf(v.w) };
    *(ushort4v*)(words_bf + ((size_t)t * B + b) * E + i) = o;
}

// feas0_bf[b][v] = bf16(mean_r visual[b][r][v])
__global__ __launch_bounds__(256) void feas0_k(
    const float* __restrict__ visual, bf16_t* __restrict__ feas0_bf)
{
    int idx = blockIdx.x * 256 + threadIdx.x;
    if (idx >= B * VIS) return;
    int b = idx >> 11, v = idx & (VIS - 1);
    float s = 0.f;
    for (int r = 0; r < R; ++r) s += visual[((size_t)b * R + r) * VIS + v];
    feas0_bf[idx] = f2bf(s * (1.0f / R));
}

// Fused per-step attention: ah = h@Wh^T, scores, softmax, ctx (bf16 out)
// h input is fp32 (precision-critical: softmax alpha is sensitive to h error).
__global__ __launch_bounds__(256) void fused_att(
    const float* __restrict__ h, const bf16_t* __restrict__ Wh_bf,
    const float* __restrict__ att_fea, const float* __restrict__ att_bias,
    const float* __restrict__ Ww, const bf16_t* __restrict__ visual_bf,
    bf16_t* __restrict__ ctx_bf)
{
    int b = blockIdx.x, tid = threadIdx.x;
    __shared__ float hs[D];
    __shared__ float ah_s[ATT];
    __shared__ float sc_s[R];
    __shared__ float alpha_s[R];

    ((float4*)hs)[tid] = ((const float4*)(h + (size_t)b * D))[tid];  // 256*4 = 1024
    __syncthreads();

    #pragma unroll 2
    for (int a = tid; a < ATT; a += 256) {
        const bf16_t* wrow = Wh_bf + (size_t)a * D;
        float s = 0.f;
        for (int k = 0; k < D; k += 8) {
            short8 wv = *(const short8*)(wrow + k);
            float4 ha = *(const float4*)&hs[k];
            float4 hb = *(const float4*)&hs[k + 4];
            s = fmaf(bf2f((bf16_t)wv[0]), ha.x, s);
            s = fmaf(bf2f((bf16_t)wv[1]), ha.y, s);
            s = fmaf(bf2f((bf16_t)wv[2]), ha.z, s);
            s = fmaf(bf2f((bf16_t)wv[3]), ha.w, s);
            s = fmaf(bf2f((bf16_t)wv[4]), hb.x, s);
            s = fmaf(bf2f((bf16_t)wv[5]), hb.y, s);
            s = fmaf(bf2f((bf16_t)wv[6]), hb.z, s);
            s = fmaf(bf2f((bf16_t)wv[7]), hb.w, s);
        }
        ah_s[a] = s;
    }
    __syncthreads();

    int wave = tid >> 6, lane = tid & 63;
    for (int r = wave; r < R; r += 4) {
        float ab = att_bias[r];
        const float* af = att_fea + ((size_t)b * R + r) * ATT;
        float s = 0.f;
        for (int a = lane; a < ATT; a += 64) {
            float v = af[a] + ah_s[a] + ab;
            s = fmaf(fmaxf(v, 0.f), Ww[a], s);
        }
        #pragma unroll
        for (int off = 32; off; off >>= 1) s += __shfl_down(s, off);
        if (lane == 0) sc_s[r] = s;
    }
    __syncthreads();

    if (tid < 64) {
        float v = (tid < R) ? sc_s[tid] : -INFINITY;
        float m = v;
        #pragma unroll
        for (int off = 32; off; off >>= 1) m = fmaxf(m, __shfl_down(m, off));
        m = __shfl(m, 0);
        float e = (tid < R) ? expf(v - m) : 0.f;
        float ss = e;
        #pragma unroll
        for (int off = 32; off; off >>= 1) ss += __shfl_down(ss, off);
        ss = __shfl(ss, 0);
        if (tid < R) alpha_s[tid] = e / ss;
    }
    __syncthreads();

    {
        int v0 = tid * 8;
        float acc[8] = {};
        for (int r = 0; r < R; ++r) {
            float al = alpha_s[r];
            short8 vv = *(const short8*)(visual_bf + ((size_t)b * R + r) * VIS + v0);
            #pragma unroll
            for (int j = 0; j < 8; ++j)
                acc[j] = fmaf(al, bf2f((bf16_t)vv[j]), acc[j]);
        }
        short8 o;
        #pragma unroll
        for (int j = 0; j < 8; ++j) o[j] = (short)f2bf(acc[j]);
        *(short8*)(ctx_bf + (size_t)b * VIS + v0) = o;
    }
}

extern "C" void kernel_launch(void* const* d_in, const int* in_sizes, int n_in,
                              void* d_out, int out_size, void* d_ws, size_t ws_size,
                              hipStream_t stream) {
    const float* visual   = (const float*)d_in[0];
    const float* joint    = (const float*)d_in[1];
    const int*   captions = (const int*)d_in[2];
    const int*   lengths  = (const int*)d_in[3];
    const float* embed_W  = (const float*)d_in[5];
    const float* Wih      = (const float*)d_in[6];
    const float* bih      = (const float*)d_in[7];
    const float* Whh      = (const float*)d_in[8];
    const float* bhh      = (const float*)d_in[9];
    const float* W_init_h = (const float*)d_in[10];
    const float* b_init_h = (const float*)d_in[11];
    const float* W_init_c = (const float*)d_in[12];
    const float* b_init_c = (const float*)d_in[13];
    const float* Wv       = (const float*)d_in[14];
    const float* Wh       = (const float*)d_in[15];
    const float* att_bias = (const float*)d_in[16];
    const float* Ww       = (const float*)d_in[17];
    const float* Wout     = (const float*)d_in[18];
    const float* bout     = (const float*)d_in[19];
    float* out = (float*)d_out;

    // ---- workspace carve-up ----
    char* cur = (char*)d_ws;
    auto alloc = [&](size_t bytes) { char* p = cur; cur += (bytes + 15) & ~size_t(15); return p; };
    float*  att_fea  = (float*)alloc((size_t)B * R * ATT * 4);
    float*  wordsW   = (float*)alloc((size_t)T * B * G4 * 4);
    float*  hf       = (float*)alloc((size_t)B * D * 4);
    float*  c_st     = (float*)alloc((size_t)B * D * 4);
    bf16_t* words_bf = (bf16_t*)alloc((size_t)T * B * E * 2);
    bf16_t* h_ping0  = (bf16_t*)alloc((size_t)B * D * 2);
    bf16_t* h_ping1  = (bf16_t*)alloc((size_t)B * D * 2);
    bf16_t* hseq_bf  = (bf16_t*)alloc((size_t)T * B * D * 2);
    bf16_t* ctx_bf   = (bf16_t*)alloc((size_t)B * VIS * 2);
    bf16_t* feas0_bf = (bf16_t*)alloc((size_t)B * VIS * 2);
    bf16_t* visual_bf= (bf16_t*)alloc((size_t)B * R * VIS * 2);
    bf16_t* Wv_bf    = (bf16_t*)alloc((size_t)ATT * VIS * 2);
    bf16_t* Wh_bf    = (bf16_t*)alloc((size_t)ATT * D * 2);
    bf16_t* Whh_bf   = (bf16_t*)alloc((size_t)G4 * D * 2);
    bf16_t* Wih_v_bf = (bf16_t*)alloc((size_t)G4 * VIS * 2);
    bf16_t* Wih_w_bf = (bf16_t*)alloc((size_t)G4 * E * 2);
    bf16_t* Wout_bf  = (bf16_t*)alloc((size_t)V * D * 2);

    auto cast = [&](const float* s, bf16_t* dst, int rows, int cols, int ld) {
        int total = rows * (cols >> 2);
        cast_bf16_k<<<(total + 255) / 256, 256, 0, stream>>>(s, dst, rows, cols, ld);
    };
    cast(visual, visual_bf, 1, B * R * VIS, B * R * VIS);
    cast(Wv,  Wv_bf,  ATT, VIS, VIS);
    cast(Wh,  Wh_bf,  ATT, D, D);
    cast(Whh, Whh_bf, G4, D, D);
    cast(Wih, Wih_v_bf, G4, VIS, VIS + E);
    cast(Wih + VIS, Wih_w_bf, G4, E, VIS + E);
    cast(Wout, Wout_bf, V, D, D);

    embed_k<<<B * T, 128, 0, stream>>>(captions, embed_W, words_bf);
    feas0_k<<<(B * VIS + 255) / 256, 256, 0, stream>>>(visual, feas0_bf);

    // h0/c0 (fp32 seed)
    gemm_nt<<<dim3(D / TILE, B / TILE), 256, 0, stream>>>(joint, W_init_h, b_init_h, hf, B, D, MM);
    gemm_nt<<<dim3(D / TILE, B / TILE), 256, 0, stream>>>(joint, W_init_c, b_init_c, c_st, B, D, MM);
    cast(hf, h_ping0, 1, B * D, B * D);

    // att_fea = visual @ Wv^T (fp32 out)
    mfma_gemm_lds<0><<<dim3(ATT / 128, (B * R) / 128), 256, 0, stream>>>(
        visual_bf, Wv_bf, nullptr, nullptr, att_fea, B * R, ATT, VIS, ATT);

    // wordsW = words @ Wih_w^T (all steps)
    mfma_gemm_lds<0><<<dim3(G4 / 128, (T * B) / 128), 256, 0, stream>>>(
        words_bf, Wih_w_bf, nullptr, nullptr, wordsW, T * B, G4, E, G4);

    // ---- recurrence (h bf16 ping-pong: read buf[t&1], write buf[(t+1)&1]) ----
    bf16_t* h_buf[2] = { h_ping0, h_ping1 };
    for (int t = 0; t < T; ++t) {
        const bf16_t* A1 = feas0_bf;
        if (t > 0) {
            fused_att<<<B, 256, 0, stream>>>(hf, Wh_bf, att_fea, att_bias, Ww, visual_bf, ctx_bf);
            A1 = ctx_bf;
        }
        gates_lstm<<<dim3(D / 8, B / 64), 256, 0, stream>>>(
            A1, h_buf[t & 1], Wih_v_bf, Whh_bf, bih, bhh,
            wordsW, lengths, c_st, hf, h_buf[(t + 1) & 1], hseq_bf, t);
    }

    // ---- deferred vocab projection ----
    mfma_gemm_lds<2><<<dim3((V + 127) / 128, (T * B) / 128), 256, 0, stream>>>(
        hseq_bf, Wout_bf, bout, lengths, out, T * B, V, D, V);
}

// Round 6
// 1865.110 us; speedup vs baseline: 3.8607x; 1.1435x over previous
//
#include <hip/hip_runtime.h>
#include <math.h>

// Problem constants (fixed by reference)
#define B 128
#define R 36
#define VIS 2048
#define MM 1024
#define E 512
#define ATT 512
#define D 1024
#define V 10000
#define MAXLEN 20
#define T 19          // MAXLEN - 1
#define G4 4096       // 4*D

typedef unsigned short bf16_t;
typedef __attribute__((ext_vector_type(8))) short short8;
typedef __attribute__((ext_vector_type(4))) float f32x4;
typedef __attribute__((ext_vector_type(4))) unsigned short ushort4v;

__device__ __forceinline__ bf16_t f2bf(float f) {
    unsigned u = __float_as_uint(f);
    u += 0x7fff + ((u >> 16) & 1);   // round-to-nearest-even
    return (bf16_t)(u >> 16);
}
__device__ __forceinline__ float bf2f(bf16_t b) {
    return __uint_as_float(((unsigned)b) << 16);
}
__device__ __forceinline__ float sigmoidf_(float x) { return 1.0f / (1.0f + expf(-x)); }

// Async global->LDS, 16B per lane. LDS dest = wave-uniform base + lane*16.
__device__ __forceinline__ void stage16(const bf16_t* g, bf16_t* lds_wave_base, int lane) {
#if defined(__has_builtin) && __has_builtin(__builtin_amdgcn_global_load_lds)
    __builtin_amdgcn_global_load_lds(
        (const __attribute__((address_space(1))) void*)g,
        (__attribute__((address_space(3))) void*)lds_wave_base, 16, 0, 0);
#else
    *(short8*)(lds_wave_base + lane * 8) = *(const short8*)g;
#endif
}

// ---------------------------------------------------------------------------
// 128x128-tile bf16 MFMA GEMM, m97 structure.
// MODE 0: C[m*ldc+n] = acc (+bias)               (fp32 out)
// MODE 2: m = t*B+b; out[(b*T+t)*V+n] = mask ? acc+bias : 0
//         (grid SWAPPED: x = m-tiles, y = n-tiles, so consecutive blocks
//          share the same Wout n-tile -> better L2/L3 reuse)
// MODE 3: bf16 out: ((bf16*)C)[m*ldc+n] = bf16(acc)
// ---------------------------------------------------------------------------
template<int MODE>
__global__ __launch_bounds__(256) void mfma_gemm_lds(
    const bf16_t* __restrict__ A, const bf16_t* __restrict__ W,
    const float* __restrict__ bias, const int* __restrict__ lengths,
    float* __restrict__ C, int M, int N, int K, int ldc)
{
    __shared__ __align__(16) bf16_t As[128 * 32];
    __shared__ __align__(16) bf16_t Ws[128 * 32];
    const int tid = threadIdx.x;
    const int wave = tid >> 6, lane = tid & 63;
    const int wm = wave >> 1, wn = wave & 1;
    const int quad = lane >> 4, l16 = lane & 15;
    const int m0 = (MODE == 2 ? blockIdx.x : blockIdx.y) * 128;
    const int n0 = (MODE == 2 ? blockIdx.y : blockIdx.x) * 128;

    f32x4 acc[4][4];
    #pragma unroll
    for (int i = 0; i < 4; ++i)
        #pragma unroll
        for (int j = 0; j < 4; ++j)
            acc[i][j] = (f32x4){0.f, 0.f, 0.f, 0.f};

    for (int kk = 0; kk < K; kk += 32) {
        #pragma unroll
        for (int i = 0; i < 2; ++i) {
            int c = tid + i * 256;          // chunk 0..511
            int row = c >> 2, seg = c & 3;
            int m = m0 + row; if (m >= M) m = M - 1;
            stage16(A + (size_t)m * K + kk + seg * 8, &As[(i * 256 + wave * 64) * 8], lane);
            int n = n0 + row; if (n >= N) n = N - 1;
            stage16(W + (size_t)n * K + kk + seg * 8, &Ws[(i * 256 + wave * 64) * 8], lane);
        }
        __syncthreads();
        short8 af[4], bfr[4];
        #pragma unroll
        for (int fm = 0; fm < 4; ++fm)
            af[fm] = *(const short8*)&As[(wm * 64 + fm * 16 + l16) * 32 + quad * 8];
        #pragma unroll
        for (int fn = 0; fn < 4; ++fn)
            bfr[fn] = *(const short8*)&Ws[(wn * 64 + fn * 16 + l16) * 32 + quad * 8];
        #pragma unroll
        for (int fm = 0; fm < 4; ++fm)
            #pragma unroll
            for (int fn = 0; fn < 4; ++fn)
                acc[fm][fn] = __builtin_amdgcn_mfma_f32_16x16x32_bf16(
                    af[fm], bfr[fn], acc[fm][fn], 0, 0, 0);
        __syncthreads();
    }

    #pragma unroll
    for (int fm = 0; fm < 4; ++fm) {
        #pragma unroll
        for (int fn = 0; fn < 4; ++fn) {
            #pragma unroll
            for (int r = 0; r < 4; ++r) {
                int m = m0 + wm * 64 + fm * 16 + quad * 4 + r;
                int n = n0 + wn * 64 + fn * 16 + l16;
                if (m >= M || n >= N) continue;
                float v = acc[fm][fn][r];
                if (MODE == 0) {
                    if (bias) v += bias[n];
                    C[(size_t)m * ldc + n] = v;
                } else if (MODE == 2) {
                    int t = m >> 7, b = m & 127;
                    v = (t < lengths[b]) ? (v + bias[n]) : 0.f;
                    C[((size_t)b * T + t) * V + n] = v;
                } else {
                    ((bf16_t*)C)[(size_t)m * ldc + n] = f2bf(v);
                }
            }
        }
    }
}

// ---------------------------------------------------------------------------
// Fused per-step attention + P-contraction:
//   t>0: ah = h@Wh^T, scores, softmax alpha;  t==0: alpha = 1/R uniform.
//   partial[b,n] = sum_r alpha[b,r] * P[b,r,n] + wordsW[t,b,n]
// P = visual @ Wih_v^T (precomputed, bf16). One block per b.
// ---------------------------------------------------------------------------
__global__ __launch_bounds__(256) void fused_att_p(
    const float* __restrict__ h, const bf16_t* __restrict__ Wh_bf,
    const float* __restrict__ att_fea, const float* __restrict__ att_bias,
    const float* __restrict__ Ww, const bf16_t* __restrict__ P_bf,
    const float* __restrict__ wordsW, float* __restrict__ partial, int t)
{
    int b = blockIdx.x, tid = threadIdx.x;
    __shared__ float hs[D];
    __shared__ float ah_s[ATT];
    __shared__ float sc_s[R];
    __shared__ float alpha_s[R];

    if (t > 0) {
        ((float4*)hs)[tid] = ((const float4*)(h + (size_t)b * D))[tid];
        __syncthreads();

        #pragma unroll 2
        for (int a = tid; a < ATT; a += 256) {
            const bf16_t* wrow = Wh_bf + (size_t)a * D;
            float s = 0.f;
            for (int k = 0; k < D; k += 8) {
                short8 wv = *(const short8*)(wrow + k);
                float4 ha = *(const float4*)&hs[k];
                float4 hb = *(const float4*)&hs[k + 4];
                s = fmaf(bf2f((bf16_t)wv[0]), ha.x, s);
                s = fmaf(bf2f((bf16_t)wv[1]), ha.y, s);
                s = fmaf(bf2f((bf16_t)wv[2]), ha.z, s);
                s = fmaf(bf2f((bf16_t)wv[3]), ha.w, s);
                s = fmaf(bf2f((bf16_t)wv[4]), hb.x, s);
                s = fmaf(bf2f((bf16_t)wv[5]), hb.y, s);
                s = fmaf(bf2f((bf16_t)wv[6]), hb.z, s);
                s = fmaf(bf2f((bf16_t)wv[7]), hb.w, s);
            }
            ah_s[a] = s;
        }
        __syncthreads();

        int wave = tid >> 6, lane = tid & 63;
        for (int r = wave; r < R; r += 4) {
            float ab = att_bias[r];
            const float* af = att_fea + ((size_t)b * R + r) * ATT;
            float s = 0.f;
            for (int a = lane; a < ATT; a += 64) {
                float v = af[a] + ah_s[a] + ab;
                s = fmaf(fmaxf(v, 0.f), Ww[a], s);
            }
            #pragma unroll
            for (int off = 32; off; off >>= 1) s += __shfl_down(s, off);
            if (lane == 0) sc_s[r] = s;
        }
        __syncthreads();

        if (tid < 64) {
            float v = (tid < R) ? sc_s[tid] : -INFINITY;
            float m = v;
            #pragma unroll
            for (int off = 32; off; off >>= 1) m = fmaxf(m, __shfl_down(m, off));
            m = __shfl(m, 0);
            float e = (tid < R) ? expf(v - m) : 0.f;
            float ss = e;
            #pragma unroll
            for (int off = 32; off; off >>= 1) ss += __shfl_down(ss, off);
            ss = __shfl(ss, 0);
            if (tid < R) alpha_s[tid] = e / ss;
        }
    } else {
        if (tid < R) alpha_s[tid] = 1.0f / R;
    }
    __syncthreads();

    // partial[b, n0:n0+16] = sum_r alpha[r] * P[b,r,n0:16] + wordsW[t,b,n0:16]
    const int n0 = tid * 16;                 // 256 * 16 = 4096 = G4
    float acc[16];
    #pragma unroll
    for (int j = 0; j < 16; ++j) acc[j] = 0.f;
    const bf16_t* Pb = P_bf + (size_t)b * R * G4 + n0;
    #pragma unroll 4
    for (int r = 0; r < R; ++r) {
        float al = alpha_s[r];
        short8 p0 = *(const short8*)(Pb + (size_t)r * G4);
        short8 p1 = *(const short8*)(Pb + (size_t)r * G4 + 8);
        #pragma unroll
        for (int j = 0; j < 8; ++j) {
            acc[j]     = fmaf(al, bf2f((bf16_t)p0[j]), acc[j]);
            acc[8 + j] = fmaf(al, bf2f((bf16_t)p1[j]), acc[8 + j]);
        }
    }
    const float* wsl = wordsW + ((size_t)t * B + b) * G4 + n0;
    float* po = partial + (size_t)b * G4 + n0;
    #pragma unroll
    for (int j = 0; j < 16; j += 4) {
        float4 w = *(const float4*)(wsl + j);
        float4 o = { acc[j] + w.x, acc[j + 1] + w.y, acc[j + 2] + w.z, acc[j + 3] + w.w };
        *(float4*)(po + j) = o;
    }
}

// ---------------------------------------------------------------------------
// Per-step h-GEMM + LSTM pointwise (K = D = 1024 only; visual part is in
// `partial`). Block (blockIdx.x = d-tile of 8, blockIdx.y = m-tile of 64)
// computes the 32 gathered gate columns {g*D+d0+r} for 64 batch rows.
// h ping-pong: h_in and h_out are DISTINCT buffers (race-free).
// ---------------------------------------------------------------------------
__global__ __launch_bounds__(256) void gates_lstm(
    const bf16_t* __restrict__ h_in,    // B x D bf16 (step t-1)
    const bf16_t* __restrict__ Whh,     // G4 x D
    const float* __restrict__ bih, const float* __restrict__ bhh,
    const float* __restrict__ partial,  // B x G4 (alpha.P + wordsW[t])
    const int* __restrict__ lengths,
    float* __restrict__ c_st,           // B x D fp32 (in/out)
    float* __restrict__ h_f32,          // B x D fp32 (in/out, for attention)
    bf16_t* __restrict__ h_out,         // B x D bf16 (step t)
    bf16_t* __restrict__ hseq,          // (t*B+m)*D
    int t)
{
    __shared__ __align__(16) bf16_t As[64 * 32];
    __shared__ __align__(16) bf16_t Ws[32 * 32];
    const int tid = threadIdx.x;
    const int wave = tid >> 6, lane = tid & 63;
    const int quad = lane >> 4, l16 = lane & 15;
    const int d0 = blockIdx.x * 8;
    const int m0 = blockIdx.y * 64;

    f32x4 acc0 = (f32x4){0.f, 0.f, 0.f, 0.f};
    f32x4 acc1 = (f32x4){0.f, 0.f, 0.f, 0.f};

    const int arow = tid >> 2, aseg = tid & 3;   // A chunk (64 rows x 4 segs)
    const int wrr = tid >> 2, wseg = tid & 3;    // W chunk (32 rows x 4 segs)
    const int wg = wrr >> 3, wr = wrr & 7;
    const int wrow_v = wg * D + d0 + wr;         // gathered weight row

    for (int kt = 0; kt < 32; ++kt) {
        int koff = kt * 32;
        stage16(h_in + (size_t)(m0 + arow) * D + koff + aseg * 8, &As[wave * 64 * 8], lane);
        if (wave < 2)
            stage16(Whh + (size_t)wrow_v * D + koff + wseg * 8, &Ws[wave * 64 * 8], lane);
        __syncthreads();

        short8 af = *(const short8*)&As[(wave * 16 + l16) * 32 + quad * 8];
        short8 b0 = *(const short8*)&Ws[(l16) * 32 + quad * 8];
        short8 b1 = *(const short8*)&Ws[(16 + l16) * 32 + quad * 8];
        acc0 = __builtin_amdgcn_mfma_f32_16x16x32_bf16(af, b0, acc0, 0, 0, 0);
        acc1 = __builtin_amdgcn_mfma_f32_16x16x32_bf16(af, b1, acc1, 0, 0, 0);
        __syncthreads();
    }

    const int d = d0 + (l16 & 7);
    const int gsel = l16 >> 3;               // 0: gates {0,2}=(i,g); 1: {1,3}=(f,o)
    const int col0 = gsel * D + d;
    const int col1 = (2 + gsel) * D + d;
    const float bia0 = bih[col0] + bhh[col0];
    const float bia1 = bih[col1] + bhh[col1];

    #pragma unroll
    for (int r = 0; r < 4; ++r) {
        int m = m0 + wave * 16 + quad * 4 + r;
        size_t pb = (size_t)m * G4;
        float v0 = acc0[r] + bia0 + partial[pb + col0];
        float v1 = acc1[r] + bia1 + partial[pb + col1];
        float w0 = __shfl_xor(v0, 8);
        float w1 = __shfl_xor(v1, 8);
        float iv, fv, gv, ov;
        if (gsel == 0) { iv = v0; gv = v1; fv = w0; ov = w1; }
        else           { fv = v0; ov = v1; iv = w0; gv = w1; }
        float ig = sigmoidf_(iv), fg = sigmoidf_(fv);
        float gg = tanhf(gv),     og = sigmoidf_(ov);
        size_t off = (size_t)m * D + d;
        if (gsel == 0) {
            float c_old = c_st[off];
            float h_old = h_f32[off];
            float cn = fmaf(fg, c_old, ig * gg);
            float hn = og * tanhf(cn);
            bool msk = t < lengths[m];
            float cv = msk ? cn : c_old;
            float hv = msk ? hn : h_old;
            c_st[off] = cv;
            h_f32[off] = hv;
            bf16_t hb = f2bf(hv);
            h_out[off] = hb;
            hseq[((size_t)t * B + m) * D + d] = hb;
        }
    }
}

// fp32 tile GEMM for the tiny one-shot h0/c0 init:  C = A@W^T + bias
#define TILE 64
#define KT 16
__global__ __launch_bounds__(256) void gemm_nt(
    const float* __restrict__ A, const float* __restrict__ W,
    const float* __restrict__ bias, float* __restrict__ C,
    int M, int N, int K)
{
    __shared__ float Asf[KT][TILE];
    __shared__ float Wsf[KT][TILE];
    const int tid = threadIdx.x;
    const int tx = tid & 15, ty = tid >> 4;
    const int m0 = blockIdx.y * TILE;
    const int n0 = blockIdx.x * TILE;
    const int lr = tid >> 2;
    const int lc = (tid & 3) * 4;
    float acc[4][4] = {};
    for (int kk = 0; kk < K; kk += KT) {
        {
            int m = m0 + lr;
            float4 v = make_float4(0.f, 0.f, 0.f, 0.f);
            if (m < M) v = *(const float4*)(A + (size_t)m * K + kk + lc);
            Asf[lc + 0][lr] = v.x; Asf[lc + 1][lr] = v.y;
            Asf[lc + 2][lr] = v.z; Asf[lc + 3][lr] = v.w;
        }
        {
            int n = n0 + lr;
            float4 v = make_float4(0.f, 0.f, 0.f, 0.f);
            if (n < N) v = *(const float4*)(W + (size_t)n * K + kk + lc);
            Wsf[lc + 0][lr] = v.x; Wsf[lc + 1][lr] = v.y;
            Wsf[lc + 2][lr] = v.z; Wsf[lc + 3][lr] = v.w;
        }
        __syncthreads();
        #pragma unroll
        for (int k = 0; k < KT; ++k) {
            float a[4], w[4];
            #pragma unroll
            for (int i = 0; i < 4; ++i) a[i] = Asf[k][ty * 4 + i];
            #pragma unroll
            for (int j = 0; j < 4; ++j) w[j] = Wsf[k][tx * 4 + j];
            #pragma unroll
            for (int i = 0; i < 4; ++i)
                #pragma unroll
                for (int j = 0; j < 4; ++j)
                    acc[i][j] = fmaf(a[i], w[j], acc[i][j]);
        }
        __syncthreads();
    }
    #pragma unroll
    for (int i = 0; i < 4; ++i) {
        int m = m0 + ty * 4 + i;
        if (m >= M) continue;
        #pragma unroll
        for (int j = 0; j < 4; ++j) {
            int n = n0 + tx * 4 + j;
            if (n >= N) continue;
            C[(size_t)m * N + n] = acc[i][j] + (bias ? bias[n] : 0.f);
        }
    }
}

// Strided fp32 -> bf16 cast
__global__ __launch_bounds__(256) void cast_bf16_k(
    const float* __restrict__ src, bf16_t* __restrict__ dst,
    int rows, int cols, int ld)
{
    int idx = blockIdx.x * 256 + threadIdx.x;
    int total = rows * (cols >> 2);
    if (idx >= total) return;
    int cq = cols >> 2;
    int r = idx / cq, c4 = (idx - r * cq) * 4;
    float4 v = *(const float4*)(src + (size_t)r * ld + c4);
    ushort4v o = { f2bf(v.x), f2bf(v.y), f2bf(v.z), f2bf(v.w) };
    *(ushort4v*)(dst + (size_t)r * cols + c4) = o;
}

// words_bf[(t*B+b)*E + :] = bf16(embed_W[captions[b][t]][:])
__global__ __launch_bounds__(128) void embed_k(
    const int* __restrict__ captions, const float* __restrict__ embed_W,
    bf16_t* __restrict__ words_bf)
{
    int bt = blockIdx.x;
    int b = bt / T, t = bt - b * T;
    int tok = captions[b * MAXLEN + t];
    int i = threadIdx.x * 4;
    float4 v = *(const float4*)(embed_W + (size_t)tok * E + i);
    ushort4v o = { f2bf(v.x), f2bf(v.y), f2bf(v.z), f2bf(v.w) };
    *(ushort4v*)(words_bf + ((size_t)t * B + b) * E + i) = o;
}

extern "C" void kernel_launch(void* const* d_in, const int* in_sizes, int n_in,
                              void* d_out, int out_size, void* d_ws, size_t ws_size,
                              hipStream_t stream) {
    const float* visual   = (const float*)d_in[0];
    const float* joint    = (const float*)d_in[1];
    const int*   captions = (const int*)d_in[2];
    const int*   lengths  = (const int*)d_in[3];
    const float* embed_W  = (const float*)d_in[5];
    const float* Wih      = (const float*)d_in[6];
    const float* bih      = (const float*)d_in[7];
    const float* Whh      = (const float*)d_in[8];
    const float* bhh      = (const float*)d_in[9];
    const float* W_init_h = (const float*)d_in[10];
    const float* b_init_h = (const float*)d_in[11];
    const float* W_init_c = (const float*)d_in[12];
    const float* b_init_c = (const float*)d_in[13];
    const float* Wv       = (const float*)d_in[14];
    const float* Wh       = (const float*)d_in[15];
    const float* att_bias = (const float*)d_in[16];
    const float* Ww       = (const float*)d_in[17];
    const float* Wout     = (const float*)d_in[18];
    const float* bout     = (const float*)d_in[19];
    float* out = (float*)d_out;

    // ---- workspace carve-up ----
    char* cur = (char*)d_ws;
    auto alloc = [&](size_t bytes) { char* p = cur; cur += (bytes + 15) & ~size_t(15); return p; };
    float*  att_fea  = (float*)alloc((size_t)B * R * ATT * 4);       // 9.4 MB
    float*  wordsW   = (float*)alloc((size_t)T * B * G4 * 4);        // 39.8 MB
    float*  partial  = (float*)alloc((size_t)B * G4 * 4);            // 2.1 MB
    float*  hf       = (float*)alloc((size_t)B * D * 4);
    float*  c_st     = (float*)alloc((size_t)B * D * 4);
    bf16_t* words_bf = (bf16_t*)alloc((size_t)T * B * E * 2);
    bf16_t* h_ping0  = (bf16_t*)alloc((size_t)B * D * 2);
    bf16_t* h_ping1  = (bf16_t*)alloc((size_t)B * D * 2);
    bf16_t* hseq_bf  = (bf16_t*)alloc((size_t)T * B * D * 2);        // 5 MB
    bf16_t* P_bf     = (bf16_t*)alloc((size_t)B * R * G4 * 2);       // 37.7 MB
    bf16_t* visual_bf= (bf16_t*)alloc((size_t)B * R * VIS * 2);      // 18.9 MB
    bf16_t* Wv_bf    = (bf16_t*)alloc((size_t)ATT * VIS * 2);
    bf16_t* Wh_bf    = (bf16_t*)alloc((size_t)ATT * D * 2);
    bf16_t* Whh_bf   = (bf16_t*)alloc((size_t)G4 * D * 2);
    bf16_t* Wih_v_bf = (bf16_t*)alloc((size_t)G4 * VIS * 2);
    bf16_t* Wih_w_bf = (bf16_t*)alloc((size_t)G4 * E * 2);
    bf16_t* Wout_bf  = (bf16_t*)alloc((size_t)V * D * 2);

    auto cast = [&](const float* s, bf16_t* dst, int rows, int cols, int ld) {
        int total = rows * (cols >> 2);
        cast_bf16_k<<<(total + 255) / 256, 256, 0, stream>>>(s, dst, rows, cols, ld);
    };
    cast(visual, visual_bf, 1, B * R * VIS, B * R * VIS);
    cast(Wv,  Wv_bf,  ATT, VIS, VIS);
    cast(Wh,  Wh_bf,  ATT, D, D);
    cast(Whh, Whh_bf, G4, D, D);
    cast(Wih, Wih_v_bf, G4, VIS, VIS + E);
    cast(Wih + VIS, Wih_w_bf, G4, E, VIS + E);
    cast(Wout, Wout_bf, V, D, D);

    embed_k<<<B * T, 128, 0, stream>>>(captions, embed_W, words_bf);

    // h0/c0 (fp32 seed)
    gemm_nt<<<dim3(D / TILE, B / TILE), 256, 0, stream>>>(joint, W_init_h, b_init_h, hf, B, D, MM);
    gemm_nt<<<dim3(D / TILE, B / TILE), 256, 0, stream>>>(joint, W_init_c, b_init_c, c_st, B, D, MM);
    cast(hf, h_ping0, 1, B * D, B * D);

    // att_fea = visual @ Wv^T (fp32 out)
    mfma_gemm_lds<0><<<dim3(ATT / 128, (B * R) / 128), 256, 0, stream>>>(
        visual_bf, Wv_bf, nullptr, nullptr, att_fea, B * R, ATT, VIS, ATT);

    // wordsW = words @ Wih_w^T (all steps)
    mfma_gemm_lds<0><<<dim3(G4 / 128, (T * B) / 128), 256, 0, stream>>>(
        words_bf, Wih_w_bf, nullptr, nullptr, wordsW, T * B, G4, E, G4);

    // P = visual @ Wih_v^T (bf16 out)  -- the key precompute: the visual
    // part of the gates becomes a per-step alpha-weighted sum over P rows.
    mfma_gemm_lds<3><<<dim3(G4 / 128, (B * R) / 128), 256, 0, stream>>>(
        visual_bf, Wih_v_bf, nullptr, nullptr, (float*)P_bf, B * R, G4, VIS, G4);

    // ---- recurrence (h bf16 ping-pong) ----
    bf16_t* h_buf[2] = { h_ping0, h_ping1 };
    for (int t = 0; t < T; ++t) {
        fused_att_p<<<B, 256, 0, stream>>>(
            hf, Wh_bf, att_fea, att_bias, Ww, P_bf, wordsW, partial, t);
        gates_lstm<<<dim3(D / 8, B / 64), 256, 0, stream>>>(
            h_buf[t & 1], Whh_bf, bih, bhh, partial, lengths,
            c_st, hf, h_buf[(t + 1) & 1], hseq_bf, t);
    }

    // ---- deferred vocab projection (grid swapped: x=m-tiles, y=n-tiles) ----
    mfma_gemm_lds<2><<<dim3((T * B) / 128, (V + 127) / 128), 256, 0, stream>>>(
        hseq_bf, Wout_bf, bout, lengths, out, T * B, V, D, V);
}